// Round 11
// baseline (1064.411 us; speedup 1.0000x reference)
//
#include <hip/hip_runtime.h>

#define T_STEPS 1000
#define NB 256
#define DZ 64
#define DH 256
#define DS 16
#define CHUNK 64
#define NCHUNK 16   // 15 full chunks of 64 + last chunk of 40 = exactly 1000 steps

// LDS-only barrier: drains lgkmcnt (LDS ordering) but NOT vmcnt.
// Safe: global loads land in private regs; global stores are never read back.
__device__ __forceinline__ void barrier_lgkm() {
    asm volatile("s_waitcnt lgkmcnt(0)\n\ts_barrier" ::: "memory");
}

// Packed fp32 pair + 16-byte pair-of-pairs (keeps ds_read_b128 loads).
typedef float fp2 __attribute__((ext_vector_type(2)));
struct __align__(16) fp2x2 { fp2 lo, hi; };

// v_pk_fma_f32: d = a*b + c on a float2 in ONE issue slot (VOP3P).
__device__ __forceinline__ fp2 pk_fma(fp2 a, fp2 b, fp2 c) {
    fp2 d;
    asm("v_pk_fma_f32 %0, %1, %2, %3" : "=v"(d) : "v"(a), "v"(b), "v"(c));
    return d;
}

// VALU-pipe cross-lane add via DPP (fuses to v_add_f32_dpp).
// CTRL: 0xB1 = quad_perm[1,0,3,2] (xor1); 0x4E = quad_perm[2,3,0,1] (xor2);
//       0x121/0x122/0x124/0x128 = row_ror 1/2/4/8.
template<int CTRL>
__device__ __forceinline__ float dpp_add(float x) {
    int y = __builtin_amdgcn_update_dpp(0, __float_as_int(x), CTRL, 0xF, 0xF, true);
    return x + __int_as_float(y);
}
// Sum across the 16 lanes of a DPP row (every lane ends with the row total).
__device__ __forceinline__ float row16_allsum(float x) {
    x = dpp_add<0x128>(x);   // += ror8
    x = dpp_add<0x124>(x);   // += ror4
    x = dpp_add<0x122>(x);   // += ror2
    x = dpp_add<0x121>(x);   // += ror1
    return x;
}

// ROUND-17: twin-block stall interleaving, CLEAN codegen retry.
// Round-10's 935us was a spill artifact, not a refutation: waves_per_eu(8,8)
// forced a 64-VGPR RA budget -> 32-VGPR body, weights spilled to scratch
// (WRITE_SIZE +90MB = spill writes; per-step reloads hid in L2). Occupancy
// DID hit 80% -- two 16-wave blocks co-reside. This round keeps the proven
// round-8 codegen (waves_per_eu min=4 -> 128-VGPR budget -> 52 VGPR, no
// spill; max=8 declares the intent) and re-runs the experiment: grid 512,
// blocks (2b,2b+1) both compute trial b redundantly (issue is cheap),
// storing alternating chunks. Hardware occupancy comes from actual usage
// (52 VGPR <= 64 -> 8 waves/EU legal). When twin A stalls at its barrier,
// twin B issues; one-time s_sleep(10) anti-phase stagger on odd twins.
// Decision rule: >= 535us clean => interleaving exhausted, round-8 is the
// floor, revert + declare roofline.
__global__ __launch_bounds__(1024)
__attribute__((amdgpu_waves_per_eu(4, 8)))
void plrnn_scan(const float* __restrict__ z0, const float* __restrict__ s,
                const float* __restrict__ A,  const float* __restrict__ W1,
                const float* __restrict__ W2, const float* __restrict__ h1,
                const float* __restrict__ h2, const float* __restrict__ C,
                float* __restrict__ out)
{
    const int tid = threadIdx.x;
    const int b   = blockIdx.x >> 1;     // trial: two blocks per trial
    const int par = blockIdx.x & 1;      // which chunks this block stores
    const int h   = tid >> 2;            // phase-1 hidden unit (quad-owned)
    const int q   = tid & 3;             // which 16-wide quarter of the W1 dot
    const int j   = tid >> 4;            // phase-2 z output (row-owned), 0..63
    const int r4  = tid & 15;            // lane within row = 16-h slice

    __shared__ __align__(16) float z_sh[DZ];
    __shared__ __align__(16) float za_sh[320];        // skew: idx = h + (h>>4)*4
    __shared__ __align__(16) float s_sh[CHUNK * DS];  // 64 steps of s[t][b][0..15]

    // ---- loop-invariant weights (32 floats + C scalar), packed as fp2 pairs ----
    fp2x2 w1v[4];    // W1[b][h][16q .. +16)  == 16 consecutive floats at 16*tid
    {
        const fp2x2* p = (const fp2x2*)(W1 + (size_t)b * DH * DZ) + 4 * tid;
        #pragma unroll
        for (int k = 0; k < 4; ++k) w1v[k] = p[k];
    }
    fp2x2 w2v[4];    // W2[b][j][16*r4 .. +16) == 16 consecutive floats at 16*tid
    {
        const fp2x2* p = (const fp2x2*)(W2 + (size_t)b * DZ * DH) + 4 * tid;
        #pragma unroll
        for (int k = 0; k < 4; ++k) w2v[k] = p[k];
    }
    const float cj  = C[tid];             // C[j][r4]: DZ*DS == 1024 == blockDim

    // med3-relu constants: za = med3(sgn*p + off, lo, hi)
    const float h1r  = h1[h];
    const float rsgn = (h1r > 0.f) ?  1.f : -1.f;
    const float roff = (h1r > 0.f) ?  h1r :  0.f;
    const float rlo  = fminf(h1r, 0.f);
    const float rhi  = fmaxf(h1r, 0.f);

    const float Aj    = A[j];
    const float h2j16 = h2[j] * 0.0625f;  // h2[j]/16, folded into the reduce
    float zr = z0[b * DZ + j];            // z state for the row's j (replicated x16)

    if (tid < DZ) z_sh[tid] = z0[b * DZ + tid];

    // s prefetch: thread tid holds s[t0+srow][b][scol] for the NEXT chunk
    const int srow = tid >> 4, scol = tid & 15;
    float sreg = s[(size_t)min(srow, T_STEPS - 1) * NB * DS + (size_t)b * DS + scol];

    const int zi = h + ((h >> 4) << 2);   // skewed za_sh index for phase-1 store
    float* outp = out + (size_t)b * DZ + j;   // advanced by NB*DZ per step

    __syncthreads();

    // Anti-phase stagger: odd twin sleeps ~640cy (~half a step) once, so the
    // two co-resident blocks' barrier stalls interleave instead of colliding.
    if (par) asm volatile("s_sleep 10");

    for (int ci = 0; ci < NCHUNK; ++ci) {
        const int t0 = ci * CHUNK;
        const int nt = (ci == NCHUNK - 1) ? (T_STEPS - t0) : CHUNK;   // 64 or 40
        const bool st = ((ci & 1) == par);   // this block stores this chunk
        s_sh[tid] = sreg;                 // visible after this step's barrier A
        {
            int tl = min(t0 + CHUNK + srow, T_STEPS - 1);
            sreg = s[(size_t)tl * NB * DS + (size_t)b * DS + scol];
        }

        #pragma unroll 4
        for (int tt = 0; tt < nt; ++tt) {
            // ---- phase 1: Wz[h] = W1 row · z (LDS b128 broadcast reads) ----
            const fp2x2* z2 = (const fp2x2*)(z_sh + 16 * q);
            fp2 ac0 = {0.f, 0.f}, ac1 = {0.f, 0.f};
            #pragma unroll
            for (int k = 0; k < 4; ++k) {
                fp2x2 zv = z2[k];
                ac0 = pk_fma(w1v[k].lo, zv.lo, ac0);
                ac1 = pk_fma(w1v[k].hi, zv.hi, ac1);
            }
            fp2 acs = ac0 + ac1;          // v_pk_add_f32
            float p1 = acs.x + acs.y;
            p1 = dpp_add<0xB1>(p1);       // quad butterfly: += lane^1
            p1 = dpp_add<0x4E>(p1);       //                 += lane^2
            float za = __builtin_amdgcn_fmed3f(fmaf(rsgn, p1, roff), rlo, rhi);
            if (q == 0) za_sh[zi] = za;
            barrier_lgkm();               // A: za_sh (+ s_sh at chunk start) visible

            // ---- phase 2: row computes z_new[j] over full h ----
            const fp2x2* q4 = (const fp2x2*)(za_sh + 20 * r4);  // skewed 16-slice
            float sv = s_sh[tt * DS + r4];                      // this lane's s elem
            fp2 pc0 = {0.f, 0.f}, pc1 = {0.f, 0.f};
            #pragma unroll
            for (int k = 0; k < 4; ++k) {
                fp2x2 v = q4[k];
                pc0 = pk_fma(w2v[k].lo, v.lo, pc0);
                pc1 = pk_fma(w2v[k].hi, v.hi, pc1);
            }
            fp2 pcs = pc0 + pc1;          // v_pk_add_f32
            float pa = (pcs.x + pcs.y) + fmaf(cj, sv, h2j16);   // fold C·s + h2/16
            pa = row16_allsum(pa);        // VALU DPP rotation reduce (no LDS)

            // ---- epilogue: every lane of the row holds the full sum ----
            float zn = fmaf(Aj, zr, pa);
            zr = zn;
            if (r4 == 0) {
                z_sh[j] = zn;             // both twins maintain state
                if (st) *outp = zn;       // only the parity owner stores
            }
            outp += NB * DZ;
            barrier_lgkm();               // B: z_sh update visible for next phase 1
        }
    }
}

extern "C" void kernel_launch(void* const* d_in, const int* in_sizes, int n_in,
                              void* d_out, int out_size, void* d_ws, size_t ws_size,
                              hipStream_t stream) {
    const float* z0p = (const float*)d_in[0];
    const float* sp  = (const float*)d_in[1];
    const float* Ap  = (const float*)d_in[2];
    const float* W1p = (const float*)d_in[3];
    const float* W2p = (const float*)d_in[4];
    const float* h1p = (const float*)d_in[5];
    const float* h2p = (const float*)d_in[6];
    const float* Cp  = (const float*)d_in[7];

    plrnn_scan<<<dim3(2 * NB), dim3(1024), 0, stream>>>(z0p, sp, Ap, W1p, W2p, h1p, h2p, Cp,
                                                        (float*)d_out);
}

// Round 12
// 572.172 us; speedup vs baseline: 1.8603x; 1.8603x over previous
//
#include <hip/hip_runtime.h>

#define T_STEPS 1000
#define NB 256
#define DZ 64
#define DH 256
#define DS 16
#define CHUNK 64
#define NCHUNK 16   // 15 full chunks of 64 + last chunk of 40 = exactly 1000 steps

// LDS-only barrier: drains lgkmcnt (LDS ordering) but NOT vmcnt.
// Safe: global loads land in private regs; global stores are never read back.
__device__ __forceinline__ void barrier_lgkm() {
    asm volatile("s_waitcnt lgkmcnt(0)\n\ts_barrier" ::: "memory");
}

// VALU-pipe cross-lane add via DPP (fuses to v_add_f32_dpp).
// CTRL: 0xB1 = quad_perm[1,0,3,2] (xor1); 0x4E = quad_perm[2,3,0,1] (xor2);
//       0x121/0x122/0x124/0x128 = row_ror 1/2/4/8.
template<int CTRL>
__device__ __forceinline__ float dpp_add(float x) {
    int y = __builtin_amdgcn_update_dpp(0, __float_as_int(x), CTRL, 0xF, 0xF, true);
    return x + __int_as_float(y);
}
// Sum across the 16 lanes of a DPP row (every lane ends with the row total).
__device__ __forceinline__ float row16_allsum(float x) {
    x = dpp_add<0x128>(x);   // += ror8
    x = dpp_add<0x124>(x);   // += ror4
    x = dpp_add<0x122>(x);   // += ror2
    x = dpp_add<0x121>(x);   // += ror1
    return x;
}

// One block per trial b; 1024 threads = 16 waves = 4 waves/SIMD.
// FINAL (round-18 revert-to-best): this is the round-12 kernel, the measured
// optimum (bench 570.5us, rocprof 533.9-537.9us). The full structural map,
// each branch measured and falsified:
//  - atomic 1-barrier:        3.0x worse (LDS same-address RMW serialization)
//  - uniform-A algebra (G):   2.1x worse (4x exchange volume + bank conflicts)
//  - LDS-byte reduction 4x:   +19% (VALU-bound; LDS broadcast reads are cheap)
//  - pk_fma issue halving:    flat (VALUBusy 68->48, duration unchanged)
//  - twin redundant blocks:   2x (waves_per_eu min sets GRANTED VGPRs ->
//                             SPI can't pack; min=8 makes the RA spill)
// Residual ~1300 cy/step = ~300 issue + ~1000 serial exchange latency:
// 2 x [ds_write drain ~120 + 16-wave barrier arrival spread ~250 + ds_read
// ~120] on a strictly alternating h-space/z-space dependency. No pipe is
// saturated (VALU 68%, LDS pipe ~50%, HBM 2%) -- a latency floor of the
// 1000-step serial recurrence. 1280 cy/step / 2.4GHz = 533us = measured.
__global__ __launch_bounds__(1024)
__attribute__((amdgpu_waves_per_eu(4, 4)))
void plrnn_scan(const float* __restrict__ z0, const float* __restrict__ s,
                const float* __restrict__ A,  const float* __restrict__ W1,
                const float* __restrict__ W2, const float* __restrict__ h1,
                const float* __restrict__ h2, const float* __restrict__ C,
                float* __restrict__ out)
{
    const int tid = threadIdx.x;
    const int b   = blockIdx.x;
    const int h   = tid >> 2;            // phase-1 hidden unit (quad-owned)
    const int q   = tid & 3;             // which 16-wide quarter of the W1 dot
    const int j   = tid >> 4;            // phase-2 z output (row-owned), 0..63
    const int r4  = tid & 15;            // lane within row = 16-h slice

    __shared__ __align__(16) float z_sh[DZ];
    __shared__ __align__(16) float za_sh[320];        // skew: idx = h + (h>>4)*4
    __shared__ __align__(16) float s_sh[CHUNK * DS];  // 64 steps of s[t][b][0..15]

    // ---- loop-invariant weights (32 floats + C scalar) ----
    float4 w1v[4];    // W1[b][h][16q .. +16)  == 16 consecutive floats at 16*tid
    {
        const float4* p = (const float4*)(W1 + (size_t)b * DH * DZ) + 4 * tid;
        #pragma unroll
        for (int k = 0; k < 4; ++k) w1v[k] = p[k];
    }
    float4 w2v[4];    // W2[b][j][16*r4 .. +16) == 16 consecutive floats at 16*tid
    {
        const float4* p = (const float4*)(W2 + (size_t)b * DZ * DH) + 4 * tid;
        #pragma unroll
        for (int k = 0; k < 4; ++k) w2v[k] = p[k];
    }
    const float cj  = C[tid];             // C[j][r4]: DZ*DS == 1024 == blockDim

    // med3-relu constants: za = med3(sgn*p + off, lo, hi)
    const float h1r  = h1[h];
    const float rsgn = (h1r > 0.f) ?  1.f : -1.f;
    const float roff = (h1r > 0.f) ?  h1r :  0.f;
    const float rlo  = fminf(h1r, 0.f);
    const float rhi  = fmaxf(h1r, 0.f);

    const float Aj    = A[j];
    const float h2j16 = h2[j] * 0.0625f;  // h2[j]/16, folded into the reduce
    float zr = z0[b * DZ + j];            // z state for the row's j (replicated x16)

    if (tid < DZ) z_sh[tid] = z0[b * DZ + tid];

    // s prefetch: thread tid holds s[t0+srow][b][scol] for the NEXT chunk
    const int srow = tid >> 4, scol = tid & 15;
    float sreg = s[(size_t)min(srow, T_STEPS - 1) * NB * DS + (size_t)b * DS + scol];

    const int zi = h + ((h >> 4) << 2);   // skewed za_sh index for phase-1 store
    float* outp = out + (size_t)b * DZ + j;   // advanced by NB*DZ per step

    __syncthreads();

    for (int ci = 0; ci < NCHUNK; ++ci) {
        const int t0 = ci * CHUNK;
        const int nt = (ci == NCHUNK - 1) ? (T_STEPS - t0) : CHUNK;   // 64 or 40
        s_sh[tid] = sreg;                 // visible after this step's barrier A
        {
            int tl = min(t0 + CHUNK + srow, T_STEPS - 1);
            sreg = s[(size_t)tl * NB * DS + (size_t)b * DS + scol];
        }

        #pragma unroll 4
        for (int tt = 0; tt < nt; ++tt) {
            // ---- phase 1: Wz[h] = W1 row · z (LDS broadcast reads, free) ----
            const float4* z4 = (const float4*)(z_sh + 16 * q);
            float a0 = 0.f, a1 = 0.f, a2 = 0.f, a3 = 0.f;
            #pragma unroll
            for (int k = 0; k < 4; ++k) {
                float4 zv = z4[k];
                a0 = fmaf(w1v[k].x, zv.x, a0);
                a1 = fmaf(w1v[k].y, zv.y, a1);
                a2 = fmaf(w1v[k].z, zv.z, a2);
                a3 = fmaf(w1v[k].w, zv.w, a3);
            }
            float p1 = (a0 + a1) + (a2 + a3);
            p1 = dpp_add<0xB1>(p1);       // quad butterfly: += lane^1
            p1 = dpp_add<0x4E>(p1);       //                 += lane^2
            float za = __builtin_amdgcn_fmed3f(fmaf(rsgn, p1, roff), rlo, rhi);
            if (q == 0) za_sh[zi] = za;
            barrier_lgkm();               // A: za_sh (+ s_sh at chunk start) visible

            // ---- phase 2: row computes z_new[j] over full h ----
            const float4* q4 = (const float4*)(za_sh + 20 * r4);  // skewed 16-slice
            float sv = s_sh[tt * DS + r4];                        // this lane's s elem
            float p00 = fmaf(cj, sv, h2j16);                      // C·s + h2/16 folded
            float p01 = 0.f, p02 = 0.f, p03 = 0.f;
            #pragma unroll
            for (int k = 0; k < 4; ++k) {
                float4 v = q4[k];
                p00 = fmaf(w2v[k].x, v.x, p00);
                p01 = fmaf(w2v[k].y, v.y, p01);
                p02 = fmaf(w2v[k].z, v.z, p02);
                p03 = fmaf(w2v[k].w, v.w, p03);
            }
            float pa = (p00 + p01) + (p02 + p03);
            pa = row16_allsum(pa);        // VALU DPP rotation reduce (no LDS)

            // ---- epilogue: every lane of the row holds the full sum ----
            float zn = fmaf(Aj, zr, pa);
            zr = zn;
            if (r4 == 0) {
                z_sh[j] = zn;
                *outp = zn;               // every computed step is a real step
            }
            outp += NB * DZ;
            barrier_lgkm();               // B: z_sh update visible for next phase 1
        }
    }
}

extern "C" void kernel_launch(void* const* d_in, const int* in_sizes, int n_in,
                              void* d_out, int out_size, void* d_ws, size_t ws_size,
                              hipStream_t stream) {
    const float* z0p = (const float*)d_in[0];
    const float* sp  = (const float*)d_in[1];
    const float* Ap  = (const float*)d_in[2];
    const float* W1p = (const float*)d_in[3];
    const float* W2p = (const float*)d_in[4];
    const float* h1p = (const float*)d_in[5];
    const float* h2p = (const float*)d_in[6];
    const float* Cp  = (const float*)d_in[7];

    plrnn_scan<<<dim3(NB), dim3(1024), 0, stream>>>(z0p, sp, Ap, W1p, W2p, h1p, h2p, Cp,
                                                    (float*)d_out);
}